// Round 12
// baseline (182.337 us; speedup 1.0000x reference)
//
#include <hip/hip_runtime.h>
#include <hip/hip_bf16.h>
#include <cstdint>

// ---------------------------------------------------------------------------
// TagProjector fused kernel (R12):
//   flat = tab[clamp(ids,0)]                  [51200, 512]  (gather, f32->bf16)
//   h    = gelu_tanh(flat @ w1 + b1)          [51200, 1024] (bf16 MFMA)
//   y    = h @ w2 + b2                        [51200, 256]  (bf16 MFMA, reg acc)
//   out  = mask ? 0 : y / max(||y||, 1e-12)   [51200, 256]  f32
//
// R12 = R11 with register-pressure + scheduling fixes:
//   1. W rotations 4-slot -> 3-slot (read ks%3, load (ks+2)%3; collision-free
//      mod 3): -16 VGPR. Target: peak live < 128 => spill fully gone.
//   2. wr1 init for chunk c+1 issued INSIDE GEMM2(c) (slots 0,1 at s2=0,1):
//      next GEMM1's first k-steps covered by ~300cyc of GEMM2 work.
//   3. wr2 init still hoisted above GELU/barrier (R11 win).
// Decisive counters: WRITE_SIZE == 51.2MB, FETCH ~= 73MB (no scratch).
// ---------------------------------------------------------------------------

typedef __bf16 bf16;
typedef bf16  bf16x8 __attribute__((ext_vector_type(8)));
typedef bf16  bf16x4 __attribute__((ext_vector_type(4)));
typedef float f32x4  __attribute__((ext_vector_type(4)));

#define D_IN    512
#define D_HID   1024
#define D_OUT   256
#define MT      64        // rows per full tile
#define RPB     200       // rows per block (51200 / 256)
#define NBLK    256
#define CHUNK   256       // N1 chunk width
#define NCH     4         // D_HID / CHUNK
#define NKS1    16        // D_IN / 32
#define NKS2C   8         // CHUNK / 32
#define THREADS 512

// strides in w1f/w2f fragment space (bf16 elems)
#define W1_C_STRIDE  131072   // 16 col-tiles * 8192
#define W1_T_STRIDE  8192     // 16 ks * 512
#define W2_T_STRIDE  16384    // 32 ks * 512
#define KS_STRIDE    512      // 64 lanes * 8

// LDS layout (bytes)
#define OFF_A    0                          // 64*512*2       = 65536 (A tile, swizzled)
#define OFF_H    65536                      // 2 * 64*256*2   = 65536 (H chunk dbuf)
#define OFF_NS   (65536 + 65536)            // 64*8*4         = 2048  (norm partials)
#define OFF_RID  (65536 + 65536 + 2048)     // 64*4           = 256   (row ids)
#define LDS_TOTAL (65536 + 65536 + 2048 + 256)   // 133376 -> 1 block/CU

// ws layout: W1f bf16 [64 ct][16 ks][64 lane][8]  (1 MB)
//            W2f bf16 [16 ct][32 ks][64 lane][8]  (512 KB)
#define W1F_ELEMS (64 * 16 * 64 * 8)   // 524288

__device__ __forceinline__ float gelu_tanh(float x) {
  // jax.nn.gelu default (approximate=True): 0.5x(1+tanh(u)) == x*sigmoid(2u)
  float u = 0.7978845608028654f * (x + 0.044715f * x * x * x);
  return x * __builtin_amdgcn_rcpf(1.0f + __expf(-2.0f * u));
}

// ------------------- prep: f32 weights -> bf16 fragment order -------------------
__global__ void prep_weights(const float* __restrict__ w1, const float* __restrict__ w2,
                             bf16* __restrict__ w1f, bf16* __restrict__ w2f) {
  const int t = blockIdx.x * blockDim.x + threadIdx.x;
  if (t < 65536) {                       // W1: 64 ct * 16 ks * 64 lanes
    const int l  = t & 63;
    const int ks = (t >> 6) & 15;
    const int ct = t >> 10;
    const int col   = ct * 16 + (l & 15);
    const int kbase = ks * 32 + (l >> 4) * 8;
    bf16x8 o;
#pragma unroll
    for (int j = 0; j < 8; ++j) o[j] = (bf16)w1[(size_t)(kbase + j) * D_HID + col];
    *(bf16x8*)(w1f + (size_t)t * 8) = o;
  } else if (t < 65536 + 32768) {        // W2: 16 ct * 32 ks * 64 lanes
    const int t2 = t - 65536;
    const int l   = t2 & 63;
    const int ks2 = (t2 >> 6) & 31;
    const int ct2 = t2 >> 11;
    const int col   = ct2 * 16 + (l & 15);
    const int kbase = ks2 * 32 + (l >> 4) * 8;
    bf16x8 o;
#pragma unroll
    for (int j = 0; j < 8; ++j) o[j] = (bf16)w2[(size_t)(kbase + j) * D_OUT + col];
    *(bf16x8*)(w2f + (size_t)t2 * 8) = o;
  }
}

// ----------------------------- tile body ---------------------------------
// RT: number of 16-row sub-tiles (4 = full 64-row tile, 1 = 16-row tail)
// RV: valid rows in this tile (ids reads + stores masked beyond RV)
template<int RT, int RV>
__device__ __forceinline__ void process_tile(
    const float* __restrict__ tab, const int* __restrict__ ids,
    const bf16* __restrict__ w1f, const bf16* __restrict__ w2f,
    const float* __restrict__ b1, const float* __restrict__ b2,
    float* __restrict__ out,
    bf16* As, bf16* Hb, float* Ns, int* Rid,
    int row0, int tid, int w, int l, int lg, int lc) {

  __syncthreads();  // previous tile's epilogue fully done (Rid/Ns reads)

  // ---- A gather: 64 rows x 512 f32 -> bf16 swizzled LDS (8 thr/row) ----
  {
    const int row = tid >> 3;        // 0..63
    const int q   = tid & 7;
    int id = -1;
    if (RV == MT || row < RV) id = ids[row0 + row];   // no OOB reads on tail
    if (q == 0) Rid[row] = id;
    const float* src = tab + (size_t)(id < 0 ? 0 : id) * D_IN;
#pragma unroll
    for (int i = 0; i < 16; ++i) {
      const int c4 = i * 32 + q * 4;
      const float4 v = *(const float4*)(src + c4);
      bf16x4 b;
      b[0] = (bf16)v.x; b[1] = (bf16)v.y; b[2] = (bf16)v.z; b[3] = (bf16)v.w;
      *(bf16x4*)&As[row * 512 + (c4 ^ ((row & 15) << 3))] = b;
    }
  }
  __syncthreads();

  // persistent GEMM2 accumulators: rows rt*16+lg*4+r, cols (w*2+t)*16+lc
  f32x4 acc2[RT][2];
#pragma unroll
  for (int rt = 0; rt < RT; ++rt)
#pragma unroll
    for (int t = 0; t < 2; ++t) acc2[rt][t] = (f32x4){0.f, 0.f, 0.f, 0.f};

  // wr1 lives across the chunk loop; init (slots 0,1) for c=0 here.
  const bf16* w1p = w1f + ((size_t)(w * 2) * W1_T_STRIDE) + (size_t)l * 8;
  bf16x8 wr1[3][2];
#pragma unroll
  for (int pf = 0; pf < 2; ++pf)
#pragma unroll
    for (int t = 0; t < 2; ++t)
      wr1[pf][t] = *(const bf16x8*)(w1p + (size_t)t * W1_T_STRIDE + (size_t)pf * KS_STRIDE);

  for (int c = 0; c < NCH; ++c) {
    bf16* Hs = Hb + (c & 1) * (MT * CHUNK);

    // ===== GEMM1: h_chunk = A @ W1[:, c*256:+256] =====
    // 3-slot rotation, depth-2: read ks%3, load (ks+2)%3 (collision-free).
    f32x4 acc1[RT][2];
#pragma unroll
    for (int rt = 0; rt < RT; ++rt)
#pragma unroll
      for (int t = 0; t < 2; ++t) acc1[rt][t] = (f32x4){0.f, 0.f, 0.f, 0.f};

#pragma unroll
    for (int ks = 0; ks < NKS1; ++ks) {
      if (ks + 2 < NKS1) {
#pragma unroll
        for (int t = 0; t < 2; ++t)
          wr1[(ks + 2) % 3][t] =
              *(const bf16x8*)(w1p + (size_t)t * W1_T_STRIDE + (size_t)(ks + 2) * KS_STRIDE);
      }
      bf16x8 af[RT];
#pragma unroll
      for (int rt = 0; rt < RT; ++rt) {
        const int e = ks * 32 + lg * 8;
        af[rt] = *(const bf16x8*)&As[(rt * 16 + lc) * 512 + (e ^ (lc << 3))];
      }
#pragma unroll
      for (int t = 0; t < 2; ++t)
#pragma unroll
        for (int rt = 0; rt < RT; ++rt)
          acc1[rt][t] = __builtin_amdgcn_mfma_f32_16x16x32_bf16(
              af[rt], wr1[ks % 3][t], acc1[rt][t], 0, 0, 0);
    }

    // ---- GEMM2's initial W2 prefetch issued EARLY (independent of H) ----
    const bf16* w2p = w2f + (((size_t)(w * 2) * 32 + c * 8) * 64 + l) * 8;
    bf16x8 wr2[3][2];
#pragma unroll
    for (int pf = 0; pf < 2; ++pf)
#pragma unroll
      for (int t = 0; t < 2; ++t)
        wr2[pf][t] = *(const bf16x8*)(w2p + (size_t)t * W2_T_STRIDE + (size_t)pf * KS_STRIDE);

    // ---- bias + GELU -> bf16 h chunk in LDS (swizzled, double-buffered) ----
#pragma unroll
    for (int t = 0; t < 2; ++t) {
      const int pos    = w * 2 + t;
      const float bias = b1[c * CHUNK + pos * 16 + lc];
#pragma unroll
      for (int rt = 0; rt < RT; ++rt) {
#pragma unroll
        for (int r = 0; r < 4; ++r) {
          const float x  = acc1[rt][t][r] + bias;
          const float hx = gelu_tanh(x);
          const int row  = rt * 16 + lg * 4 + r;
          const int e    = pos * 16 + lc;
          Hs[row * 256 + (e ^ ((row & 15) << 3))] = (bf16)hx;
        }
      }
    }
    __syncthreads();   // h chunk visible; wr2 loads were in flight during wait

    // ===== GEMM2: y += h_chunk @ W2[c*256:+256, :] =====
    // Also issues wr1 init (slots 0,1) for chunk c+1 at s2=0,1.
    const bf16* w1p_nxt = w1p + W1_C_STRIDE;
    const bool has_next = (c + 1 < NCH);
#pragma unroll
    for (int s2 = 0; s2 < NKS2C; ++s2) {
      if (s2 + 2 < NKS2C) {
#pragma unroll
        for (int t = 0; t < 2; ++t)
          wr2[(s2 + 2) % 3][t] =
              *(const bf16x8*)(w2p + (size_t)t * W2_T_STRIDE + (size_t)(s2 + 2) * KS_STRIDE);
      }
      if (s2 < 2 && has_next) {
#pragma unroll
        for (int t = 0; t < 2; ++t)
          wr1[s2][t] =
              *(const bf16x8*)(w1p_nxt + (size_t)t * W1_T_STRIDE + (size_t)s2 * KS_STRIDE);
      }
      bf16x8 hf[RT];
#pragma unroll
      for (int rt = 0; rt < RT; ++rt) {
        const int e = s2 * 32 + lg * 8;
        hf[rt] = *(const bf16x8*)&Hs[(rt * 16 + lc) * 256 + (e ^ (lc << 3))];
      }
#pragma unroll
      for (int t = 0; t < 2; ++t)
#pragma unroll
        for (int rt = 0; rt < RT; ++rt)
          acc2[rt][t] = __builtin_amdgcn_mfma_f32_16x16x32_bf16(
              hf[rt], wr2[s2 % 3][t], acc2[rt][t], 0, 0, 0);
    }
    w1p = w1p_nxt;
  }

  // ---- epilogue: +b2, row L2-norm, pad mask, store (no yv array) ----
  float bias2[2];
  bias2[0] = b2[(w * 2 + 0) * 16 + lc];
  bias2[1] = b2[(w * 2 + 1) * 16 + lc];

  float ssq[RT][4];
#pragma unroll
  for (int rt = 0; rt < RT; ++rt)
#pragma unroll
    for (int r = 0; r < 4; ++r) ssq[rt][r] = 0.f;

#pragma unroll
  for (int t = 0; t < 2; ++t)
#pragma unroll
    for (int rt = 0; rt < RT; ++rt)
#pragma unroll
      for (int r = 0; r < 4; ++r) {
        const float v = acc2[rt][t][r] + bias2[t];
        ssq[rt][r] += v * v;
      }

#pragma unroll
  for (int rt = 0; rt < RT; ++rt)
#pragma unroll
    for (int r = 0; r < 4; ++r) {
      float s = ssq[rt][r];
      s += __shfl_xor(s, 1);
      s += __shfl_xor(s, 2);
      s += __shfl_xor(s, 4);
      s += __shfl_xor(s, 8);
      ssq[rt][r] = s;   // per-wave partial (32 of 256 cols)
    }
  if (lc == 0) {
#pragma unroll
    for (int rt = 0; rt < RT; ++rt)
#pragma unroll
      for (int r = 0; r < 4; ++r)
        Ns[(rt * 16 + lg * 4 + r) * 8 + w] = ssq[rt][r];
  }
  __syncthreads();

#pragma unroll
  for (int rt = 0; rt < RT; ++rt)
#pragma unroll
    for (int r = 0; r < 4; ++r) {
      const int row = rt * 16 + lg * 4 + r;
      if (RV == MT || row < RV) {
        float ss = 0.f;
#pragma unroll
        for (int ww = 0; ww < 8; ++ww) ss += Ns[row * 8 + ww];
        const float scale = (Rid[row] < 0) ? 0.f : (1.f / fmaxf(sqrtf(ss), 1e-12f));
#pragma unroll
        for (int t = 0; t < 2; ++t)
          out[(size_t)(row0 + row) * D_OUT + (w * 2 + t) * 16 + lc] =
              (acc2[rt][t][r] + bias2[t]) * scale;
      }
    }
}

// ----------------------------- fused main kernel --------------------------------
__global__ __launch_bounds__(THREADS, 1)
void tagproj_fused(const float* __restrict__ tab, const int* __restrict__ ids,
                   const bf16* __restrict__ w1f, const bf16* __restrict__ w2f,
                   const float* __restrict__ b1, const float* __restrict__ b2,
                   float* __restrict__ out) {
  extern __shared__ __align__(16) char lds[];
  bf16*  As  = (bf16*)(lds + OFF_A);
  bf16*  Hb  = (bf16*)(lds + OFF_H);
  float* Ns  = (float*)(lds + OFF_NS);
  int*   Rid = (int*)(lds + OFF_RID);

  const int tid = threadIdx.x;
  const int w   = tid >> 6;   // wave 0..7
  const int l   = tid & 63;
  const int lg  = l >> 4;     // k-group 0..3
  const int lc  = l & 15;     // row/col within 16-tile
  const int base = blockIdx.x * RPB;

  // 3 full 64-row tiles + one 16-row tail tile (8 valid) = 200 rows, balanced
  for (int tt = 0; tt < 3; ++tt)
    process_tile<4, MT>(tab, ids, w1f, w2f, b1, b2, out,
                        As, Hb, Ns, Rid, base + tt * MT, tid, w, l, lg, lc);
  process_tile<1, 8>(tab, ids, w1f, w2f, b1, b2, out,
                     As, Hb, Ns, Rid, base + 192, tid, w, l, lg, lc);
}

// --------------------------------- launcher ---------------------------------
extern "C" void kernel_launch(void* const* d_in, const int* in_sizes, int n_in,
                              void* d_out, int out_size, void* d_ws, size_t ws_size,
                              hipStream_t stream) {
  const float* tab = (const float*)d_in[0];
  const float* w1  = (const float*)d_in[1];
  const float* b1  = (const float*)d_in[2];
  const float* w2  = (const float*)d_in[3];
  const float* b2  = (const float*)d_in[4];
  const int*   ids = (const int*)d_in[5];
  float* out = (float*)d_out;

  bf16* w1f = (bf16*)d_ws;
  bf16* w2f = w1f + W1F_ELEMS;

  hipLaunchKernelGGL(prep_weights, dim3(384), dim3(256), 0, stream, w1, w2, w1f, w2f);

  (void)hipFuncSetAttribute(reinterpret_cast<const void*>(tagproj_fused),
                            hipFuncAttributeMaxDynamicSharedMemorySize, LDS_TOTAL);
  hipLaunchKernelGGL(tagproj_fused, dim3(NBLK), dim3(THREADS), LDS_TOTAL, stream,
                     tab, ids, w1f, w2f, b1, b2, out);
}

// Round 13
// 156.524 us; speedup vs baseline: 1.1649x; 1.1649x over previous
//
#include <hip/hip_runtime.h>
#include <hip/hip_bf16.h>
#include <cstdint>

// ---------------------------------------------------------------------------
// TagProjector fused kernel (R13):
//   flat = tab[clamp(ids,0)]                  [51200, 512]  (gather, f32->bf16)
//   h    = gelu_tanh(flat @ w1 + b1)          [51200, 1024] (bf16 MFMA)
//   y    = h @ w2 + b2                        [51200, 256]  (bf16 MFMA, reg acc)
//   out  = mask ? 0 : y / max(||y||, 1e-12)   [51200, 256]  f32
//
// R13 = R11 (best: 168us prof; depth-3 4-slot W rotations, early wr2 hoist,
// no yv array) + __attribute__((amdgpu_waves_per_eu(2,8))).
// Rationale: R9-R12 show natural register demand ~140-160 VGPR but the
// compiler pins the cap at 128 (= min-4-waves/EU heuristic) under every
// launch_bounds tried, causing persistent scratch spill (WRITE 63-75MB vs
// 51.2 ideal). LDS (133KB) already limits occupancy to 1 block/CU = 2
// waves/SIMD, so requesting waves_per_eu(2) raises the cap to 256 at zero
// occupancy cost. Decisive: VGPR_Count != 128, WRITE == 51.2MB.
// ---------------------------------------------------------------------------

typedef __bf16 bf16;
typedef bf16  bf16x8 __attribute__((ext_vector_type(8)));
typedef bf16  bf16x4 __attribute__((ext_vector_type(4)));
typedef float f32x4  __attribute__((ext_vector_type(4)));

#define D_IN    512
#define D_HID   1024
#define D_OUT   256
#define MT      64        // rows per full tile
#define RPB     200       // rows per block (51200 / 256)
#define NBLK    256
#define CHUNK   256       // N1 chunk width
#define NCH     4         // D_HID / CHUNK
#define NKS1    16        // D_IN / 32
#define NKS2C   8         // CHUNK / 32
#define THREADS 512

// LDS layout (bytes)
#define OFF_A    0                          // 64*512*2       = 65536 (A tile, swizzled)
#define OFF_H    65536                      // 2 * 64*256*2   = 65536 (H chunk dbuf)
#define OFF_NS   (65536 + 65536)            // 64*8*4         = 2048  (norm partials)
#define OFF_RID  (65536 + 65536 + 2048)     // 64*4           = 256   (row ids)
#define LDS_TOTAL (65536 + 65536 + 2048 + 256)   // 133376 -> 1 block/CU

// ws layout: W1f bf16 [64 ct][16 ks][64 lane][8]  (1 MB)
//            W2f bf16 [16 ct][32 ks][64 lane][8]  (512 KB)
#define W1F_ELEMS (64 * 16 * 64 * 8)   // 524288

__device__ __forceinline__ float gelu_tanh(float x) {
  // jax.nn.gelu default (approximate=True): 0.5x(1+tanh(u)) == x*sigmoid(2u)
  float u = 0.7978845608028654f * (x + 0.044715f * x * x * x);
  return x * __builtin_amdgcn_rcpf(1.0f + __expf(-2.0f * u));
}

// ------------------- prep: f32 weights -> bf16 fragment order -------------------
__global__ void prep_weights(const float* __restrict__ w1, const float* __restrict__ w2,
                             bf16* __restrict__ w1f, bf16* __restrict__ w2f) {
  const int t = blockIdx.x * blockDim.x + threadIdx.x;
  if (t < 65536) {                       // W1: 64 ct * 16 ks * 64 lanes
    const int l  = t & 63;
    const int ks = (t >> 6) & 15;
    const int ct = t >> 10;
    const int col   = ct * 16 + (l & 15);
    const int kbase = ks * 32 + (l >> 4) * 8;
    bf16x8 o;
#pragma unroll
    for (int j = 0; j < 8; ++j) o[j] = (bf16)w1[(size_t)(kbase + j) * D_HID + col];
    *(bf16x8*)(w1f + (size_t)t * 8) = o;
  } else if (t < 65536 + 32768) {        // W2: 16 ct * 32 ks * 64 lanes
    const int t2 = t - 65536;
    const int l   = t2 & 63;
    const int ks2 = (t2 >> 6) & 31;
    const int ct2 = t2 >> 11;
    const int col   = ct2 * 16 + (l & 15);
    const int kbase = ks2 * 32 + (l >> 4) * 8;
    bf16x8 o;
#pragma unroll
    for (int j = 0; j < 8; ++j) o[j] = (bf16)w2[(size_t)(kbase + j) * D_OUT + col];
    *(bf16x8*)(w2f + (size_t)t2 * 8) = o;
  }
}

// ----------------------------- tile body ---------------------------------
// RT: number of 16-row sub-tiles (4 = full 64-row tile, 1 = 16-row tail)
// RV: valid rows in this tile (ids reads + stores masked beyond RV)
template<int RT, int RV>
__device__ __forceinline__ void process_tile(
    const float* __restrict__ tab, const int* __restrict__ ids,
    const bf16* __restrict__ w1f, const bf16* __restrict__ w2f,
    const float* __restrict__ b1, const float* __restrict__ b2,
    float* __restrict__ out,
    bf16* As, bf16* Hb, float* Ns, int* Rid,
    int row0, int tid, int w, int l, int lg, int lc) {

  __syncthreads();  // previous tile's epilogue fully done (Rid/Ns reads)

  // ---- A gather: 64 rows x 512 f32 -> bf16 swizzled LDS (8 thr/row) ----
  {
    const int row = tid >> 3;        // 0..63
    const int q   = tid & 7;
    int id = -1;
    if (RV == MT || row < RV) id = ids[row0 + row];   // no OOB reads on tail
    if (q == 0) Rid[row] = id;
    const float* src = tab + (size_t)(id < 0 ? 0 : id) * D_IN;
#pragma unroll
    for (int i = 0; i < 16; ++i) {
      const int c4 = i * 32 + q * 4;
      const float4 v = *(const float4*)(src + c4);
      bf16x4 b;
      b[0] = (bf16)v.x; b[1] = (bf16)v.y; b[2] = (bf16)v.z; b[3] = (bf16)v.w;
      *(bf16x4*)&As[row * 512 + (c4 ^ ((row & 15) << 3))] = b;
    }
  }
  __syncthreads();

  // persistent GEMM2 accumulators: rows rt*16+lg*4+r, cols (w*2+t)*16+lc
  f32x4 acc2[RT][2];
#pragma unroll
  for (int rt = 0; rt < RT; ++rt)
#pragma unroll
    for (int t = 0; t < 2; ++t) acc2[rt][t] = (f32x4){0.f, 0.f, 0.f, 0.f};

  for (int c = 0; c < NCH; ++c) {
    bf16* Hs = Hb + (c & 1) * (MT * CHUNK);

    // ===== GEMM1: h_chunk = A @ W1[:, c*256:+256], depth-3 W prefetch =====
    f32x4 acc1[RT][2];
#pragma unroll
    for (int rt = 0; rt < RT; ++rt)
#pragma unroll
      for (int t = 0; t < 2; ++t) acc1[rt][t] = (f32x4){0.f, 0.f, 0.f, 0.f};

    // fragment: ((ct*16 + ks)*64 + l)*8, ct = c*16 + w*2 + t
    const bf16* w1p = w1f + (((size_t)(c * 16 + w * 2) * 16) * 64 + l) * 8;
    bf16x8 wr1[4][2];   // 4-slot rotation, depth-3: load (ks+3)&3, read ks&3
#pragma unroll
    for (int pf = 0; pf < 3; ++pf)
#pragma unroll
      for (int t = 0; t < 2; ++t)
        wr1[pf][t] = *(const bf16x8*)(w1p + (size_t)t * 8192 + (size_t)pf * 512);

#pragma unroll
    for (int ks = 0; ks < NKS1; ++ks) {
      if (ks + 3 < NKS1) {
#pragma unroll
        for (int t = 0; t < 2; ++t)
          wr1[(ks + 3) & 3][t] =
              *(const bf16x8*)(w1p + (size_t)t * 8192 + (size_t)(ks + 3) * 512);
      }
      bf16x8 af[RT];
#pragma unroll
      for (int rt = 0; rt < RT; ++rt) {
        const int e = ks * 32 + lg * 8;
        af[rt] = *(const bf16x8*)&As[(rt * 16 + lc) * 512 + (e ^ (lc << 3))];
      }
#pragma unroll
      for (int t = 0; t < 2; ++t)
#pragma unroll
        for (int rt = 0; rt < RT; ++rt)
          acc1[rt][t] = __builtin_amdgcn_mfma_f32_16x16x32_bf16(
              af[rt], wr1[ks & 3][t], acc1[rt][t], 0, 0, 0);
    }

    // ---- GEMM2's initial W2 prefetch issued EARLY (independent of H) ----
    const bf16* w2p = w2f + (((size_t)(w * 2) * 32 + c * 8) * 64 + l) * 8;
    bf16x8 wr2[4][2];
#pragma unroll
    for (int pf = 0; pf < 3; ++pf)
#pragma unroll
      for (int t = 0; t < 2; ++t)
        wr2[pf][t] = *(const bf16x8*)(w2p + (size_t)t * 16384 + (size_t)pf * 512);

    // ---- bias + GELU -> bf16 h chunk in LDS (swizzled, double-buffered) ----
#pragma unroll
    for (int t = 0; t < 2; ++t) {
      const int pos    = w * 2 + t;
      const float bias = b1[c * CHUNK + pos * 16 + lc];
#pragma unroll
      for (int rt = 0; rt < RT; ++rt) {
#pragma unroll
        for (int r = 0; r < 4; ++r) {
          const float x  = acc1[rt][t][r] + bias;
          const float hx = gelu_tanh(x);
          const int row  = rt * 16 + lg * 4 + r;
          const int e    = pos * 16 + lc;
          Hs[row * 256 + (e ^ ((row & 15) << 3))] = (bf16)hx;
        }
      }
    }
    __syncthreads();   // h chunk visible; wr2 loads were in flight during wait

    // ===== GEMM2: y += h_chunk @ W2[c*256:+256, :], depth-3 W prefetch =====
#pragma unroll
    for (int s2 = 0; s2 < NKS2C; ++s2) {
      if (s2 + 3 < NKS2C) {
#pragma unroll
        for (int t = 0; t < 2; ++t)
          wr2[(s2 + 3) & 3][t] =
              *(const bf16x8*)(w2p + (size_t)t * 16384 + (size_t)(s2 + 3) * 512);
      }
      bf16x8 hf[RT];
#pragma unroll
      for (int rt = 0; rt < RT; ++rt) {
        const int e = s2 * 32 + lg * 8;
        hf[rt] = *(const bf16x8*)&Hs[(rt * 16 + lc) * 256 + (e ^ (lc << 3))];
      }
#pragma unroll
      for (int t = 0; t < 2; ++t)
#pragma unroll
        for (int rt = 0; rt < RT; ++rt)
          acc2[rt][t] = __builtin_amdgcn_mfma_f32_16x16x32_bf16(
              hf[rt], wr2[s2 & 3][t], acc2[rt][t], 0, 0, 0);
    }
  }

  // ---- epilogue: +b2, row L2-norm, pad mask, store (no yv array) ----
  float bias2[2];
  bias2[0] = b2[(w * 2 + 0) * 16 + lc];
  bias2[1] = b2[(w * 2 + 1) * 16 + lc];

  float ssq[RT][4];
#pragma unroll
  for (int rt = 0; rt < RT; ++rt)
#pragma unroll
    for (int r = 0; r < 4; ++r) ssq[rt][r] = 0.f;

#pragma unroll
  for (int t = 0; t < 2; ++t)
#pragma unroll
    for (int rt = 0; rt < RT; ++rt)
#pragma unroll
      for (int r = 0; r < 4; ++r) {
        const float v = acc2[rt][t][r] + bias2[t];
        ssq[rt][r] += v * v;
      }

#pragma unroll
  for (int rt = 0; rt < RT; ++rt)
#pragma unroll
    for (int r = 0; r < 4; ++r) {
      float s = ssq[rt][r];
      s += __shfl_xor(s, 1);
      s += __shfl_xor(s, 2);
      s += __shfl_xor(s, 4);
      s += __shfl_xor(s, 8);
      ssq[rt][r] = s;   // per-wave partial (32 of 256 cols)
    }
  if (lc == 0) {
#pragma unroll
    for (int rt = 0; rt < RT; ++rt)
#pragma unroll
      for (int r = 0; r < 4; ++r)
        Ns[(rt * 16 + lg * 4 + r) * 8 + w] = ssq[rt][r];
  }
  __syncthreads();

#pragma unroll
  for (int rt = 0; rt < RT; ++rt)
#pragma unroll
    for (int r = 0; r < 4; ++r) {
      const int row = rt * 16 + lg * 4 + r;
      if (RV == MT || row < RV) {
        float ss = 0.f;
#pragma unroll
        for (int ww = 0; ww < 8; ++ww) ss += Ns[row * 8 + ww];
        const float scale = (Rid[row] < 0) ? 0.f : (1.f / fmaxf(sqrtf(ss), 1e-12f));
#pragma unroll
        for (int t = 0; t < 2; ++t)
          out[(size_t)(row0 + row) * D_OUT + (w * 2 + t) * 16 + lc] =
              (acc2[rt][t][r] + bias2[t]) * scale;
      }
    }
}

// ----------------------------- fused main kernel --------------------------------
__global__ __launch_bounds__(THREADS, 1)
__attribute__((amdgpu_waves_per_eu(2, 8)))
void tagproj_fused(const float* __restrict__ tab, const int* __restrict__ ids,
                   const bf16* __restrict__ w1f, const bf16* __restrict__ w2f,
                   const float* __restrict__ b1, const float* __restrict__ b2,
                   float* __restrict__ out) {
  extern __shared__ __align__(16) char lds[];
  bf16*  As  = (bf16*)(lds + OFF_A);
  bf16*  Hb  = (bf16*)(lds + OFF_H);
  float* Ns  = (float*)(lds + OFF_NS);
  int*   Rid = (int*)(lds + OFF_RID);

  const int tid = threadIdx.x;
  const int w   = tid >> 6;   // wave 0..7
  const int l   = tid & 63;
  const int lg  = l >> 4;     // k-group 0..3
  const int lc  = l & 15;     // row/col within 16-tile
  const int base = blockIdx.x * RPB;

  // 3 full 64-row tiles + one 16-row tail tile (8 valid) = 200 rows, balanced
  for (int tt = 0; tt < 3; ++tt)
    process_tile<4, MT>(tab, ids, w1f, w2f, b1, b2, out,
                        As, Hb, Ns, Rid, base + tt * MT, tid, w, l, lg, lc);
  process_tile<1, 8>(tab, ids, w1f, w2f, b1, b2, out,
                     As, Hb, Ns, Rid, base + 192, tid, w, l, lg, lc);
}

// --------------------------------- launcher ---------------------------------
extern "C" void kernel_launch(void* const* d_in, const int* in_sizes, int n_in,
                              void* d_out, int out_size, void* d_ws, size_t ws_size,
                              hipStream_t stream) {
  const float* tab = (const float*)d_in[0];
  const float* w1  = (const float*)d_in[1];
  const float* b1  = (const float*)d_in[2];
  const float* w2  = (const float*)d_in[3];
  const float* b2  = (const float*)d_in[4];
  const int*   ids = (const int*)d_in[5];
  float* out = (float*)d_out;

  bf16* w1f = (bf16*)d_ws;
  bf16* w2f = w1f + W1F_ELEMS;

  hipLaunchKernelGGL(prep_weights, dim3(384), dim3(256), 0, stream, w1, w2, w1f, w2f);

  (void)hipFuncSetAttribute(reinterpret_cast<const void*>(tagproj_fused),
                            hipFuncAttributeMaxDynamicSharedMemorySize, LDS_TOTAL);
  hipLaunchKernelGGL(tagproj_fused, dim3(NBLK), dim3(THREADS), LDS_TOTAL, stream,
                     tab, ids, w1f, w2f, b1, b2, out);
}

// Round 14
// 149.815 us; speedup vs baseline: 1.2171x; 1.0448x over previous
//
#include <hip/hip_runtime.h>
#include <hip/hip_bf16.h>
#include <cstdint>

// ---------------------------------------------------------------------------
// TagProjector fused kernel (R14):
//   flat = tab[clamp(ids,0)]                  [51200, 512]  (gather, f32->bf16)
//   h    = gelu_tanh(flat @ w1 + b1)          [51200, 1024] (bf16 MFMA)
//   y    = h @ w2 + b2                        [51200, 256]  (bf16 MFMA, reg acc)
//   out  = mask ? 0 : y / max(||y||, 1e-12)   [51200, 256]  f32
//
// R14 = R11 with ONE change: W rotations 4-slot/depth-3 -> 3-slot/depth-2
// (read ks%3, load (ks+2)%3; in-flight slots never collide with read slot).
// Rationale: 128 VGPR is a HARD cap on this toolchain (R9-R13: every
// launch_bounds/waves_per_eu variant pins at 128). R11 peak live ~130 ->
// chronic ~12MB scratch. 3-slot cuts 16 VGPR -> peak ~120 < 128.
// Cover stays sufficient: depth-2 x 8 MFMA/k-step ~ 310 SIMD-cyc >= L2 lat.
// Decisive counters: VGPR < 128, WRITE == 51.2MB, FETCH ~= 73MB.
// ---------------------------------------------------------------------------

typedef __bf16 bf16;
typedef bf16  bf16x8 __attribute__((ext_vector_type(8)));
typedef bf16  bf16x4 __attribute__((ext_vector_type(4)));
typedef float f32x4  __attribute__((ext_vector_type(4)));

#define D_IN    512
#define D_HID   1024
#define D_OUT   256
#define MT      64        // rows per full tile
#define RPB     200       // rows per block (51200 / 256)
#define NBLK    256
#define CHUNK   256       // N1 chunk width
#define NCH     4         // D_HID / CHUNK
#define NKS1    16        // D_IN / 32
#define NKS2C   8         // CHUNK / 32
#define THREADS 512

// LDS layout (bytes)
#define OFF_A    0                          // 64*512*2       = 65536 (A tile, swizzled)
#define OFF_H    65536                      // 2 * 64*256*2   = 65536 (H chunk dbuf)
#define OFF_NS   (65536 + 65536)            // 64*8*4         = 2048  (norm partials)
#define OFF_RID  (65536 + 65536 + 2048)     // 64*4           = 256   (row ids)
#define LDS_TOTAL (65536 + 65536 + 2048 + 256)   // 133376 -> 1 block/CU

// ws layout: W1f bf16 [64 ct][16 ks][64 lane][8]  (1 MB)
//            W2f bf16 [16 ct][32 ks][64 lane][8]  (512 KB)
#define W1F_ELEMS (64 * 16 * 64 * 8)   // 524288

__device__ __forceinline__ float gelu_tanh(float x) {
  // jax.nn.gelu default (approximate=True): 0.5x(1+tanh(u)) == x*sigmoid(2u)
  float u = 0.7978845608028654f * (x + 0.044715f * x * x * x);
  return x * __builtin_amdgcn_rcpf(1.0f + __expf(-2.0f * u));
}

// ------------------- prep: f32 weights -> bf16 fragment order -------------------
__global__ void prep_weights(const float* __restrict__ w1, const float* __restrict__ w2,
                             bf16* __restrict__ w1f, bf16* __restrict__ w2f) {
  const int t = blockIdx.x * blockDim.x + threadIdx.x;
  if (t < 65536) {                       // W1: 64 ct * 16 ks * 64 lanes
    const int l  = t & 63;
    const int ks = (t >> 6) & 15;
    const int ct = t >> 10;
    const int col   = ct * 16 + (l & 15);
    const int kbase = ks * 32 + (l >> 4) * 8;
    bf16x8 o;
#pragma unroll
    for (int j = 0; j < 8; ++j) o[j] = (bf16)w1[(size_t)(kbase + j) * D_HID + col];
    *(bf16x8*)(w1f + (size_t)t * 8) = o;
  } else if (t < 65536 + 32768) {        // W2: 16 ct * 32 ks * 64 lanes
    const int t2 = t - 65536;
    const int l   = t2 & 63;
    const int ks2 = (t2 >> 6) & 31;
    const int ct2 = t2 >> 11;
    const int col   = ct2 * 16 + (l & 15);
    const int kbase = ks2 * 32 + (l >> 4) * 8;
    bf16x8 o;
#pragma unroll
    for (int j = 0; j < 8; ++j) o[j] = (bf16)w2[(size_t)(kbase + j) * D_OUT + col];
    *(bf16x8*)(w2f + (size_t)t2 * 8) = o;
  }
}

// ----------------------------- tile body ---------------------------------
// RT: number of 16-row sub-tiles (4 = full 64-row tile, 1 = 16-row tail)
// RV: valid rows in this tile (ids reads + stores masked beyond RV)
template<int RT, int RV>
__device__ __forceinline__ void process_tile(
    const float* __restrict__ tab, const int* __restrict__ ids,
    const bf16* __restrict__ w1f, const bf16* __restrict__ w2f,
    const float* __restrict__ b1, const float* __restrict__ b2,
    float* __restrict__ out,
    bf16* As, bf16* Hb, float* Ns, int* Rid,
    int row0, int tid, int w, int l, int lg, int lc) {

  __syncthreads();  // previous tile's epilogue fully done (Rid/Ns reads)

  // ---- A gather: 64 rows x 512 f32 -> bf16 swizzled LDS (8 thr/row) ----
  {
    const int row = tid >> 3;        // 0..63
    const int q   = tid & 7;
    int id = -1;
    if (RV == MT || row < RV) id = ids[row0 + row];   // no OOB reads on tail
    if (q == 0) Rid[row] = id;
    const float* src = tab + (size_t)(id < 0 ? 0 : id) * D_IN;
#pragma unroll
    for (int i = 0; i < 16; ++i) {
      const int c4 = i * 32 + q * 4;
      const float4 v = *(const float4*)(src + c4);
      bf16x4 b;
      b[0] = (bf16)v.x; b[1] = (bf16)v.y; b[2] = (bf16)v.z; b[3] = (bf16)v.w;
      *(bf16x4*)&As[row * 512 + (c4 ^ ((row & 15) << 3))] = b;
    }
  }
  __syncthreads();

  // persistent GEMM2 accumulators: rows rt*16+lg*4+r, cols (w*2+t)*16+lc
  f32x4 acc2[RT][2];
#pragma unroll
  for (int rt = 0; rt < RT; ++rt)
#pragma unroll
    for (int t = 0; t < 2; ++t) acc2[rt][t] = (f32x4){0.f, 0.f, 0.f, 0.f};

  for (int c = 0; c < NCH; ++c) {
    bf16* Hs = Hb + (c & 1) * (MT * CHUNK);

    // ===== GEMM1: h_chunk = A @ W1[:, c*256:+256] =====
    // 3-slot rotation, depth-2: read ks%3, load (ks+2)%3 (collision-free).
    f32x4 acc1[RT][2];
#pragma unroll
    for (int rt = 0; rt < RT; ++rt)
#pragma unroll
      for (int t = 0; t < 2; ++t) acc1[rt][t] = (f32x4){0.f, 0.f, 0.f, 0.f};

    // fragment: ((ct*16 + ks)*64 + l)*8, ct = c*16 + w*2 + t
    const bf16* w1p = w1f + (((size_t)(c * 16 + w * 2) * 16) * 64 + l) * 8;
    bf16x8 wr1[3][2];
#pragma unroll
    for (int pf = 0; pf < 2; ++pf)
#pragma unroll
      for (int t = 0; t < 2; ++t)
        wr1[pf][t] = *(const bf16x8*)(w1p + (size_t)t * 8192 + (size_t)pf * 512);

#pragma unroll
    for (int ks = 0; ks < NKS1; ++ks) {
      if (ks + 2 < NKS1) {
#pragma unroll
        for (int t = 0; t < 2; ++t)
          wr1[(ks + 2) % 3][t] =
              *(const bf16x8*)(w1p + (size_t)t * 8192 + (size_t)(ks + 2) * 512);
      }
      bf16x8 af[RT];
#pragma unroll
      for (int rt = 0; rt < RT; ++rt) {
        const int e = ks * 32 + lg * 8;
        af[rt] = *(const bf16x8*)&As[(rt * 16 + lc) * 512 + (e ^ (lc << 3))];
      }
#pragma unroll
      for (int t = 0; t < 2; ++t)
#pragma unroll
        for (int rt = 0; rt < RT; ++rt)
          acc1[rt][t] = __builtin_amdgcn_mfma_f32_16x16x32_bf16(
              af[rt], wr1[ks % 3][t], acc1[rt][t], 0, 0, 0);
    }

    // ---- GEMM2's initial W2 prefetch issued EARLY (independent of H) ----
    const bf16* w2p = w2f + (((size_t)(w * 2) * 32 + c * 8) * 64 + l) * 8;
    bf16x8 wr2[3][2];
#pragma unroll
    for (int pf = 0; pf < 2; ++pf)
#pragma unroll
      for (int t = 0; t < 2; ++t)
        wr2[pf][t] = *(const bf16x8*)(w2p + (size_t)t * 16384 + (size_t)pf * 512);

    // ---- bias + GELU -> bf16 h chunk in LDS (swizzled, double-buffered) ----
#pragma unroll
    for (int t = 0; t < 2; ++t) {
      const int pos    = w * 2 + t;
      const float bias = b1[c * CHUNK + pos * 16 + lc];
#pragma unroll
      for (int rt = 0; rt < RT; ++rt) {
#pragma unroll
        for (int r = 0; r < 4; ++r) {
          const float x  = acc1[rt][t][r] + bias;
          const float hx = gelu_tanh(x);
          const int row  = rt * 16 + lg * 4 + r;
          const int e    = pos * 16 + lc;
          Hs[row * 256 + (e ^ ((row & 15) << 3))] = (bf16)hx;
        }
      }
    }
    __syncthreads();   // h chunk visible; wr2 loads were in flight during wait

    // ===== GEMM2: y += h_chunk @ W2[c*256:+256, :] =====
#pragma unroll
    for (int s2 = 0; s2 < NKS2C; ++s2) {
      if (s2 + 2 < NKS2C) {
#pragma unroll
        for (int t = 0; t < 2; ++t)
          wr2[(s2 + 2) % 3][t] =
              *(const bf16x8*)(w2p + (size_t)t * 16384 + (size_t)(s2 + 2) * 512);
      }
      bf16x8 hf[RT];
#pragma unroll
      for (int rt = 0; rt < RT; ++rt) {
        const int e = s2 * 32 + lg * 8;
        hf[rt] = *(const bf16x8*)&Hs[(rt * 16 + lc) * 256 + (e ^ (lc << 3))];
      }
#pragma unroll
      for (int t = 0; t < 2; ++t)
#pragma unroll
        for (int rt = 0; rt < RT; ++rt)
          acc2[rt][t] = __builtin_amdgcn_mfma_f32_16x16x32_bf16(
              hf[rt], wr2[s2 % 3][t], acc2[rt][t], 0, 0, 0);
    }
  }

  // ---- epilogue: +b2, row L2-norm, pad mask, store (no yv array) ----
  float bias2[2];
  bias2[0] = b2[(w * 2 + 0) * 16 + lc];
  bias2[1] = b2[(w * 2 + 1) * 16 + lc];

  float ssq[RT][4];
#pragma unroll
  for (int rt = 0; rt < RT; ++rt)
#pragma unroll
    for (int r = 0; r < 4; ++r) ssq[rt][r] = 0.f;

#pragma unroll
  for (int t = 0; t < 2; ++t)
#pragma unroll
    for (int rt = 0; rt < RT; ++rt)
#pragma unroll
      for (int r = 0; r < 4; ++r) {
        const float v = acc2[rt][t][r] + bias2[t];
        ssq[rt][r] += v * v;
      }

#pragma unroll
  for (int rt = 0; rt < RT; ++rt)
#pragma unroll
    for (int r = 0; r < 4; ++r) {
      float s = ssq[rt][r];
      s += __shfl_xor(s, 1);
      s += __shfl_xor(s, 2);
      s += __shfl_xor(s, 4);
      s += __shfl_xor(s, 8);
      ssq[rt][r] = s;   // per-wave partial (32 of 256 cols)
    }
  if (lc == 0) {
#pragma unroll
    for (int rt = 0; rt < RT; ++rt)
#pragma unroll
      for (int r = 0; r < 4; ++r)
        Ns[(rt * 16 + lg * 4 + r) * 8 + w] = ssq[rt][r];
  }
  __syncthreads();

#pragma unroll
  for (int rt = 0; rt < RT; ++rt)
#pragma unroll
    for (int r = 0; r < 4; ++r) {
      const int row = rt * 16 + lg * 4 + r;
      if (RV == MT || row < RV) {
        float ss = 0.f;
#pragma unroll
        for (int ww = 0; ww < 8; ++ww) ss += Ns[row * 8 + ww];
        const float scale = (Rid[row] < 0) ? 0.f : (1.f / fmaxf(sqrtf(ss), 1e-12f));
#pragma unroll
        for (int t = 0; t < 2; ++t)
          out[(size_t)(row0 + row) * D_OUT + (w * 2 + t) * 16 + lc] =
              (acc2[rt][t][r] + bias2[t]) * scale;
      }
    }
}

// ----------------------------- fused main kernel --------------------------------
__global__ __launch_bounds__(THREADS, 1)
void tagproj_fused(const float* __restrict__ tab, const int* __restrict__ ids,
                   const bf16* __restrict__ w1f, const bf16* __restrict__ w2f,
                   const float* __restrict__ b1, const float* __restrict__ b2,
                   float* __restrict__ out) {
  extern __shared__ __align__(16) char lds[];
  bf16*  As  = (bf16*)(lds + OFF_A);
  bf16*  Hb  = (bf16*)(lds + OFF_H);
  float* Ns  = (float*)(lds + OFF_NS);
  int*   Rid = (int*)(lds + OFF_RID);

  const int tid = threadIdx.x;
  const int w   = tid >> 6;   // wave 0..7
  const int l   = tid & 63;
  const int lg  = l >> 4;     // k-group 0..3
  const int lc  = l & 15;     // row/col within 16-tile
  const int base = blockIdx.x * RPB;

  // 3 full 64-row tiles + one 16-row tail tile (8 valid) = 200 rows, balanced
  for (int tt = 0; tt < 3; ++tt)
    process_tile<4, MT>(tab, ids, w1f, w2f, b1, b2, out,
                        As, Hb, Ns, Rid, base + tt * MT, tid, w, l, lg, lc);
  process_tile<1, 8>(tab, ids, w1f, w2f, b1, b2, out,
                     As, Hb, Ns, Rid, base + 192, tid, w, l, lg, lc);
}

// --------------------------------- launcher ---------------------------------
extern "C" void kernel_launch(void* const* d_in, const int* in_sizes, int n_in,
                              void* d_out, int out_size, void* d_ws, size_t ws_size,
                              hipStream_t stream) {
  const float* tab = (const float*)d_in[0];
  const float* w1  = (const float*)d_in[1];
  const float* b1  = (const float*)d_in[2];
  const float* w2  = (const float*)d_in[3];
  const float* b2  = (const float*)d_in[4];
  const int*   ids = (const int*)d_in[5];
  float* out = (float*)d_out;

  bf16* w1f = (bf16*)d_ws;
  bf16* w2f = w1f + W1F_ELEMS;

  hipLaunchKernelGGL(prep_weights, dim3(384), dim3(256), 0, stream, w1, w2, w1f, w2f);

  (void)hipFuncSetAttribute(reinterpret_cast<const void*>(tagproj_fused),
                            hipFuncAttributeMaxDynamicSharedMemorySize, LDS_TOTAL);
  hipLaunchKernelGGL(tagproj_fused, dim3(NBLK), dim3(THREADS), LDS_TOTAL, stream,
                     tab, ids, w1f, w2f, b1, b2, out);
}